// Round 6
// baseline (418.261 us; speedup 1.0000x reference)
//
#include <hip/hip_runtime.h>
#include <hip/hip_bf16.h>

// NodeModel: edge MLP ([x[col]||edge_attr] -> 64 relu -> 64 relu) -> scatter_mean
// over row -> node MLP ([x||agg||u[batch]] -> 64 relu -> 32).
// N=50000, E=1.6M, D_H=64.
//
// R6: software-pipelined edge kernel. Grid-stride loop keeps sorted4 metadata
// 2 tiles ahead and the 64B/lane input gather 1 tile ahead in registers, so
// the ~900-cyc random gathers hide under the current tile's MFMA+LDS+flush
// chain (R5 was serial: 11.7K cyc/tile wall latency, VALUBusy 30%).
// Sort-chain kernels vectorized to int4 (4 edges/thread).

typedef __attribute__((ext_vector_type(8))) short bf16x8;
typedef __attribute__((ext_vector_type(4))) float f32x4;

__device__ __forceinline__ unsigned short f2bf(float f) {
    union { float f; unsigned u; } v; v.f = f;
    return (unsigned short)((v.u + 0x7FFFu + ((v.u >> 16) & 1u)) >> 16);
}

// ---------------- counting sort ----------------

__global__ __launch_bounds__(256) void count_rows(
    const int* __restrict__ erow, int* __restrict__ counts, int E)
{
    const int gid = blockIdx.x * blockDim.x + threadIdx.x;
    const int stride = gridDim.x * blockDim.x;
    const int n4 = E >> 2;
    for (int i = gid; i < n4; i += stride) {
        const int4 r = ((const int4*)erow)[i];
        atomicAdd(&counts[r.x], 1);
        atomicAdd(&counts[r.y], 1);
        atomicAdd(&counts[r.z], 1);
        atomicAdd(&counts[r.w], 1);
    }
    for (int i = (n4 << 2) + gid; i < E; i += stride)
        atomicAdd(&counts[erow[i]], 1);
}

__global__ __launch_bounds__(256) void scan_blocks(
    const int* __restrict__ counts, int* __restrict__ excl,
    int* __restrict__ bsum, int N)
{
    __shared__ int tmp[256];
    const int t = threadIdx.x;
    const int i = blockIdx.x * 256 + t;
    const int v = (i < N) ? counts[i] : 0;
    tmp[t] = v; __syncthreads();
#pragma unroll
    for (int o = 1; o < 256; o <<= 1) {
        const int a = (t >= o) ? tmp[t - o] : 0;
        __syncthreads();
        tmp[t] += a;
        __syncthreads();
    }
    if (i < N) excl[i] = tmp[t] - v;
    if (t == 255) bsum[blockIdx.x] = tmp[t];
}

__global__ __launch_bounds__(256) void scan_bsum(int* __restrict__ bsum, int nb)
{
    __shared__ int tmp[256];
    const int t = threadIdx.x;
    const int v = (t < nb) ? bsum[t] : 0;
    tmp[t] = v; __syncthreads();
#pragma unroll
    for (int o = 1; o < 256; o <<= 1) {
        const int a = (t >= o) ? tmp[t - o] : 0;
        __syncthreads();
        tmp[t] += a;
        __syncthreads();
    }
    if (t < nb) bsum[t] = tmp[t] - v;   // exclusive
}

__global__ __launch_bounds__(256) void scan_add(
    int* __restrict__ rowstart, const int* __restrict__ bsum, int N, int E)
{
    const int i = blockIdx.x * 256 + threadIdx.x;
    if (i < N) rowstart[i] += bsum[blockIdx.x];
    if (i == 0) rowstart[N] = E;
}

// sorted4[pos] = {edge_id, col, row, 0}
__global__ __launch_bounds__(256) void permute_edges(
    const int* __restrict__ erow, const int* __restrict__ ecol,
    int* __restrict__ cursor, int4* __restrict__ sorted4, int E)
{
    const int gid = blockIdx.x * blockDim.x + threadIdx.x;
    const int stride = gridDim.x * blockDim.x;
    const int n4 = E >> 2;
    for (int i = gid; i < n4; i += stride) {
        const int4 r = ((const int4*)erow)[i];
        const int4 c = ((const int4*)ecol)[i];
        const int e0 = i << 2;
        int pos;
        pos = atomicAdd(&cursor[r.x], 1); sorted4[pos] = int4{e0,     c.x, r.x, 0};
        pos = atomicAdd(&cursor[r.y], 1); sorted4[pos] = int4{e0 + 1, c.y, r.y, 0};
        pos = atomicAdd(&cursor[r.z], 1); sorted4[pos] = int4{e0 + 2, c.z, r.z, 0};
        pos = atomicAdd(&cursor[r.w], 1); sorted4[pos] = int4{e0 + 3, c.w, r.w, 0};
    }
    for (int i = (n4 << 2) + gid; i < E; i += stride) {
        const int r = erow[i];
        const int pos = atomicAdd(&cursor[r], 1);
        sorted4[pos] = int4{i, ecol[i], r, 0};
    }
}

// ---------------- edge MLP (sorted, pipelined) + segment-reduced scatter ----------------

#define D2S 68   // D2 row stride (floats); breaks the 4-way store conflict

__global__ __launch_bounds__(256, 3) void edge_mlp_mfma(
    const float* __restrict__ x,        // [N,32]
    const int4*  __restrict__ sorted4,  // [E] {eid,col,row,0}
    const float* __restrict__ eattr,    // [E,32]
    const float* __restrict__ W1a,      // [64,64] (in,out)
    const float* __restrict__ b1a,      // [64]
    const float* __restrict__ W1b,      // [64,64]
    const float* __restrict__ b1b,      // [64]
    float* __restrict__ summed,         // [N,64]
    int E)
{
    __shared__ __align__(16) unsigned short In[64 * 64];   // 8KB
    __shared__ __align__(16) unsigned short H2[64 * 64];   // 8KB
    __shared__ __align__(16) float          D2[64 * D2S];  // 17KB

    const int tid  = threadIdx.x;
    const int lane = tid & 63;
    const int wv   = tid >> 6;
    const int g    = lane >> 4;
    const int el   = lane & 15;
    const int le   = lane >> 2;   // staging: local edge 0..15
    const int p    = lane & 3;    // staging: quarter of 64-wide input

    // persistent weight fragments: A row = lane&15, k = 8*(lane>>4)+j;
    // B col = lane&15, same k (identical mappings)
    bf16x8 wa[4][2], wb[4][2];
    f32x4  bias1[4];
    float  bias2s[4];
#pragma unroll
    for (int mt = 0; mt < 4; ++mt) {
        const int o = mt * 16 + el;
#pragma unroll
        for (int ks = 0; ks < 2; ++ks) {
            bf16x8 ta, tb;
#pragma unroll
            for (int j = 0; j < 8; ++j) {
                const int k = ks * 32 + 8 * g + j;
                ta[j] = (short)f2bf(W1a[k * 64 + o]);
                tb[j] = (short)f2bf(W1b[k * 64 + o]);
            }
            wa[mt][ks] = ta;
            wb[mt][ks] = tb;
        }
#pragma unroll
        for (int r = 0; r < 4; ++r) bias1[mt][r] = b1a[mt * 16 + 4 * g + r];
        bias2s[mt] = b1b[o];
    }

    unsigned short* const inrow = In + (wv * 16) * 64;
    unsigned short* const h2row = H2 + (wv * 16) * 64;
    float*          const d2row = D2 + (wv * 16) * D2S;

    const int ntile = (E + 15) >> 4;
    const int wid   = blockIdx.x * 4 + wv;
    const int nw    = gridDim.x * 4;

    // tile-meta load (sorted4 fragments needed by staging + flush)
    auto load_meta = [&](int t, int4& s4o, int& mro) {
        if (t < ntile) {
            const int ebase = t << 4;
            const int pos  = ebase + le;
            const int pos2 = ebase + el;
            s4o = (pos  < E) ? sorted4[pos] : int4{0, 0, 0, 0};
            mro = (pos2 < E) ? sorted4[pos2].z : -1;
        } else {
            s4o = int4{0, 0, 0, 0};
            mro = -1;
        }
    };
    // input gather for tile t using its meta (64B/lane)
    auto gather = [&](int t, const int4& s4, float4 vo[4]) {
        const bool valid = (t < ntile) && (((t << 4) + le) < E);
        const float* src = (p < 2) ? x + (size_t)s4.y * 32 + p * 16
                                   : eattr + (size_t)s4.x * 32 + (p - 2) * 16;
        if (valid) {
#pragma unroll
            for (int q = 0; q < 4; ++q) vo[q] = ((const float4*)src)[q];
        } else {
#pragma unroll
            for (int q = 0; q < 4; ++q) vo[q] = float4{0.f, 0.f, 0.f, 0.f};
        }
    };

    // ---- pipeline prologue: meta(t), gather(t), meta(t+nw) ----
    float4 vc[4]; int mrc;
    int4 s4p; int mrp;
    {
        int4 s4c; int mr0;
        load_meta(wid, s4c, mr0);
        gather(wid, s4c, vc);
        mrc = mr0;
        load_meta(wid + nw, s4p, mrp);
    }

    for (int t = wid; t < ntile; t += nw) {
        const int ebase = t << 4;

        // ---- prefetch issues: meta for t+2nw, gather for t+nw ----
        int4 s4p2; int mrp2;
        load_meta(t + 2 * nw, s4p2, mrp2);
        float4 vn[4];
        gather(t + nw, s4p, vn);

        // ---- stage current tile: pack vc -> bf16 -> swizzled LDS ----
        {
            bf16x8 c0, c1;
#pragma unroll
            for (int q = 0; q < 2; ++q) {
                c0[4*q+0] = (short)f2bf(vc[q].x);   c0[4*q+1] = (short)f2bf(vc[q].y);
                c0[4*q+2] = (short)f2bf(vc[q].z);   c0[4*q+3] = (short)f2bf(vc[q].w);
                c1[4*q+0] = (short)f2bf(vc[q+2].x); c1[4*q+1] = (short)f2bf(vc[q+2].y);
                c1[4*q+2] = (short)f2bf(vc[q+2].z); c1[4*q+3] = (short)f2bf(vc[q+2].w);
            }
            const int sw = le & 7;
            unsigned short* row = inrow + le * 64;
            *(bf16x8*)(row + (((2 * p)     ^ sw) * 8)) = c0;
            *(bf16x8*)(row + (((2 * p + 1) ^ sw) * 8)) = c1;
        }
        // wave-private LDS rows: compiler lgkmcnt orders write->read, no barrier

        const int sw = el & 7;

        // ---- layer 1: D1 = W1a^T (A) x In^T (B) -> neuron-major ----
        const unsigned short* brow = inrow + el * 64;
        const bf16x8 bf0 = *(const bf16x8*)(brow + (((0 + g) ^ sw) * 8));
        const bf16x8 bf1 = *(const bf16x8*)(brow + (((4 + g) ^ sw) * 8));
        f32x4 a0 = bias1[0], a1 = bias1[1], a2 = bias1[2], a3 = bias1[3];
        a0 = __builtin_amdgcn_mfma_f32_16x16x32_bf16(wa[0][0], bf0, a0, 0, 0, 0);
        a1 = __builtin_amdgcn_mfma_f32_16x16x32_bf16(wa[1][0], bf0, a1, 0, 0, 0);
        a2 = __builtin_amdgcn_mfma_f32_16x16x32_bf16(wa[2][0], bf0, a2, 0, 0, 0);
        a3 = __builtin_amdgcn_mfma_f32_16x16x32_bf16(wa[3][0], bf0, a3, 0, 0, 0);
        a0 = __builtin_amdgcn_mfma_f32_16x16x32_bf16(wa[0][1], bf1, a0, 0, 0, 0);
        a1 = __builtin_amdgcn_mfma_f32_16x16x32_bf16(wa[1][1], bf1, a1, 0, 0, 0);
        a2 = __builtin_amdgcn_mfma_f32_16x16x32_bf16(wa[2][1], bf1, a2, 0, 0, 0);
        a3 = __builtin_amdgcn_mfma_f32_16x16x32_bf16(wa[3][1], bf1, a3, 0, 0, 0);

        // ---- relu -> bf16 -> H2 (wave-private, swizzled) ----
        unsigned short* hrow = h2row + el * 64;
        {
            f32x4 accs[4] = {a0, a1, a2, a3};
#pragma unroll
            for (int mt = 0; mt < 4; ++mt) {
                unsigned short pk[4];
#pragma unroll
                for (int r = 0; r < 4; ++r) pk[r] = f2bf(fmaxf(accs[mt][r], 0.f));
                const int hid   = mt * 16 + 4 * g;
                const int chunk = hid >> 3;
                const int off   = hid & 7;
                *(uint2*)(hrow + ((chunk ^ sw) * 8 + off)) = *(uint2*)pk;
            }
        }

        // ---- layer 2, operand-swapped: D2 = H1 (A) x W1b (B) -> EDGE-major ----
        const bf16x8 hb0 = *(const bf16x8*)(hrow + (((0 + g) ^ sw) * 8));
        const bf16x8 hb1 = *(const bf16x8*)(hrow + (((4 + g) ^ sw) * 8));
        f32x4 d0 = {bias2s[0], bias2s[0], bias2s[0], bias2s[0]};
        f32x4 d1 = {bias2s[1], bias2s[1], bias2s[1], bias2s[1]};
        f32x4 d2 = {bias2s[2], bias2s[2], bias2s[2], bias2s[2]};
        f32x4 d3 = {bias2s[3], bias2s[3], bias2s[3], bias2s[3]};
        d0 = __builtin_amdgcn_mfma_f32_16x16x32_bf16(hb0, wb[0][0], d0, 0, 0, 0);
        d1 = __builtin_amdgcn_mfma_f32_16x16x32_bf16(hb0, wb[1][0], d1, 0, 0, 0);
        d2 = __builtin_amdgcn_mfma_f32_16x16x32_bf16(hb0, wb[2][0], d2, 0, 0, 0);
        d3 = __builtin_amdgcn_mfma_f32_16x16x32_bf16(hb0, wb[3][0], d3, 0, 0, 0);
        d0 = __builtin_amdgcn_mfma_f32_16x16x32_bf16(hb1, wb[0][1], d0, 0, 0, 0);
        d1 = __builtin_amdgcn_mfma_f32_16x16x32_bf16(hb1, wb[1][1], d1, 0, 0, 0);
        d2 = __builtin_amdgcn_mfma_f32_16x16x32_bf16(hb1, wb[2][1], d2, 0, 0, 0);
        d3 = __builtin_amdgcn_mfma_f32_16x16x32_bf16(hb1, wb[3][1], d3, 0, 0, 0);

        // ---- relu -> LDS [16 edges][64 neurons] f32 (stride D2S) ----
        {
            f32x4 dd[4] = {d0, d1, d2, d3};
#pragma unroll
            for (int nt = 0; nt < 4; ++nt)
#pragma unroll
                for (int r = 0; r < 4; ++r) {
                    const int eg = ebase + 4 * g + r;
                    d2row[(4 * g + r) * D2S + nt * 16 + el] =
                        (eg < E) ? fmaxf(dd[nt][r], 0.f) : 0.f;
                }
        }

        // ---- segment flush: rows are sorted runs; lane = neuron ----
        float acc = 0.f;
        int prev = __shfl(mrc, 0);
#pragma unroll
        for (int j = 0; j < 16; ++j) {
            const float v = d2row[j * D2S + lane];
            const int rj = __shfl(mrc, j);
            if (rj != prev) {                        // wave-uniform branch
                if (prev >= 0)
                    unsafeAtomicAdd(&summed[(size_t)prev * 64 + lane], acc);
                acc = 0.f;
                prev = rj;
            }
            acc += v;
        }
        if (prev >= 0)
            unsafeAtomicAdd(&summed[(size_t)prev * 64 + lane], acc);

        // ---- rotate pipeline registers ----
#pragma unroll
        for (int q = 0; q < 4; ++q) vc[q] = vn[q];
        mrc = mrp;
        s4p = s4p2;
        mrp = mrp2;
    }
}

// ---------------- node MLP via MFMA ----------------

__global__ __launch_bounds__(256, 2) void node_mlp_mfma(
    const float* __restrict__ x,        // [N,32]
    const float* __restrict__ summed,   // [N,64]
    const int*   __restrict__ rowstart, // [N+1]
    const float* __restrict__ u,        // [G,16]
    const int*   __restrict__ batch,    // [N]
    const float* __restrict__ W2a,      // [112,64]
    const float* __restrict__ b2a,      // [64]
    const float* __restrict__ W2b,      // [64,32]
    const float* __restrict__ b2b,      // [32]
    float* __restrict__ out,            // [N,32]
    int N)
{
    __shared__ __align__(16) unsigned short In[64 * 128];  // 16KB
    __shared__ __align__(16) unsigned short H[64 * 64];    // 8KB

    const int tid  = threadIdx.x;
    const int lane = tid & 63;
    const int wv   = tid >> 6;
    const int g    = lane >> 4;
    const int el   = lane & 15;

    bf16x8 wa[4][4];
    f32x4  bias1[4];
#pragma unroll
    for (int mt = 0; mt < 4; ++mt) {
        const int o = mt * 16 + el;
#pragma unroll
        for (int ks = 0; ks < 4; ++ks) {
            bf16x8 ta;
#pragma unroll
            for (int j = 0; j < 8; ++j) {
                const int k = ks * 32 + 8 * g + j;
                ta[j] = (k < 112) ? (short)f2bf(W2a[k * 64 + o]) : (short)0;
            }
            wa[mt][ks] = ta;
        }
#pragma unroll
        for (int r = 0; r < 4; ++r) bias1[mt][r] = b2a[mt * 16 + 4 * g + r];
    }
    bf16x8 wb[2][2];
    float  bias2s[2];
#pragma unroll
    for (int nt = 0; nt < 2; ++nt) {
        const int o = nt * 16 + el;
#pragma unroll
        for (int ks = 0; ks < 2; ++ks) {
            bf16x8 tb;
#pragma unroll
            for (int j = 0; j < 8; ++j) {
                const int k = ks * 32 + 8 * g + j;
                tb[j] = (short)f2bf(W2b[k * 32 + o]);
            }
            wb[nt][ks] = tb;
        }
        bias2s[nt] = b2b[o];
    }

    unsigned short* const inrow = In + (wv * 16) * 128;
    unsigned short* const hrow0 = H + (wv * 16) * 64;

    const int ntile = (N + 15) >> 4;
    const int wid   = blockIdx.x * 4 + wv;
    const int nw    = gridDim.x * 4;

    for (int t = wid; t < ntile; t += nw) {
        const int nbase = t << 4;

        // ---- stage 16 nodes: 4 lanes/node, 32-float segment each ----
        // row layout (128 bf16): [x(32) | agg(32) | agg(32) | u(16)+0(16)]
        {
            const int le = lane >> 2;
            const int p  = lane & 3;
            const int n  = nbase + le;
            float4 v[8];
            if (n < N) {
                if (p == 0) {
                    const float4* xp = (const float4*)(x + (size_t)n * 32);
#pragma unroll
                    for (int q = 0; q < 8; ++q) v[q] = xp[q];
                } else if (p < 3) {
                    const int cnt = rowstart[n + 1] - rowstart[n];
                    const float inv = 1.0f / fmaxf((float)cnt, 1.0f);
                    const float4* sp = (const float4*)(summed + (size_t)n * 64 + (p - 1) * 32);
#pragma unroll
                    for (int q = 0; q < 8; ++q) {
                        v[q] = sp[q];
                        v[q].x *= inv; v[q].y *= inv; v[q].z *= inv; v[q].w *= inv;
                    }
                } else {
                    const int gb = batch[n];
                    const float4* up = (const float4*)(u + (size_t)gb * 16);
#pragma unroll
                    for (int q = 0; q < 4; ++q) v[q] = up[q];
#pragma unroll
                    for (int q = 4; q < 8; ++q) v[q] = float4{0.f, 0.f, 0.f, 0.f};
                }
            } else {
#pragma unroll
                for (int q = 0; q < 8; ++q) v[q] = float4{0.f, 0.f, 0.f, 0.f};
            }
            const int sw = le & 7;
            unsigned short* row = inrow + le * 128;
#pragma unroll
            for (int q = 0; q < 4; ++q) {
                bf16x8 c;
                const float4 va = v[2 * q], vb = v[2 * q + 1];
                c[0] = (short)f2bf(va.x); c[1] = (short)f2bf(va.y);
                c[2] = (short)f2bf(va.z); c[3] = (short)f2bf(va.w);
                c[4] = (short)f2bf(vb.x); c[5] = (short)f2bf(vb.y);
                c[6] = (short)f2bf(vb.z); c[7] = (short)f2bf(vb.w);
                const int cc = 4 * p + q;
                const int ci = (cc & 8) | ((cc & 7) ^ sw);
                *(bf16x8*)(row + ci * 8) = c;
            }
        }

        // ---- layer 1: 16 MFMAs over K=128 ----
        const unsigned short* brow = inrow + el * 128;
        const int sw7 = el & 7;
        f32x4 a0 = bias1[0], a1 = bias1[1], a2 = bias1[2], a3 = bias1[3];
#pragma unroll
        for (int ks = 0; ks < 4; ++ks) {
            const int cc = ks * 4 + g;
            const int ci = (cc & 8) | ((cc & 7) ^ sw7);
            const bf16x8 bf = *(const bf16x8*)(brow + ci * 8);
            a0 = __builtin_amdgcn_mfma_f32_16x16x32_bf16(wa[0][ks], bf, a0, 0, 0, 0);
            a1 = __builtin_amdgcn_mfma_f32_16x16x32_bf16(wa[1][ks], bf, a1, 0, 0, 0);
            a2 = __builtin_amdgcn_mfma_f32_16x16x32_bf16(wa[2][ks], bf, a2, 0, 0, 0);
            a3 = __builtin_amdgcn_mfma_f32_16x16x32_bf16(wa[3][ks], bf, a3, 0, 0, 0);
        }

        // ---- relu -> bf16 -> H (swizzled by el&7) ----
        unsigned short* hrow = hrow0 + el * 64;
        {
            f32x4 accs[4] = {a0, a1, a2, a3};
#pragma unroll
            for (int mt = 0; mt < 4; ++mt) {
                unsigned short pk[4];
#pragma unroll
                for (int r = 0; r < 4; ++r) pk[r] = f2bf(fmaxf(accs[mt][r], 0.f));
                const int hid   = mt * 16 + 4 * g;
                const int chunk = hid >> 3;
                const int off   = hid & 7;
                *(uint2*)(hrow + ((chunk ^ sw7) * 8 + off)) = *(uint2*)pk;
            }
        }

        // ---- layer 2 operand-swapped: D = H (A) x W2b (B) -> node-major ----
        const bf16x8 hb0 = *(const bf16x8*)(hrow + (((0 + g) ^ sw7) * 8));
        const bf16x8 hb1 = *(const bf16x8*)(hrow + (((4 + g) ^ sw7) * 8));
        f32x4 dn0 = {bias2s[0], bias2s[0], bias2s[0], bias2s[0]};
        f32x4 dn1 = {bias2s[1], bias2s[1], bias2s[1], bias2s[1]};
        dn0 = __builtin_amdgcn_mfma_f32_16x16x32_bf16(hb0, wb[0][0], dn0, 0, 0, 0);
        dn1 = __builtin_amdgcn_mfma_f32_16x16x32_bf16(hb0, wb[1][0], dn1, 0, 0, 0);
        dn0 = __builtin_amdgcn_mfma_f32_16x16x32_bf16(hb1, wb[0][1], dn0, 0, 0, 0);
        dn1 = __builtin_amdgcn_mfma_f32_16x16x32_bf16(hb1, wb[1][1], dn1, 0, 0, 0);

        // ---- store: lane holds node 4g+r, out nt*16+el ----
        if (nbase + 16 <= N) {
#pragma unroll
            for (int r = 0; r < 4; ++r) {
                float* dst = out + (size_t)(nbase + 4 * g + r) * 32 + el;
                dst[0]  = dn0[r];
                dst[16] = dn1[r];
            }
        } else {
#pragma unroll
            for (int r = 0; r < 4; ++r) {
                const int n = nbase + 4 * g + r;
                if (n < N) {
                    float* dst = out + (size_t)n * 32 + el;
                    dst[0]  = dn0[r];
                    dst[16] = dn1[r];
                }
            }
        }
    }
}

extern "C" void kernel_launch(void* const* d_in, const int* in_sizes, int n_in,
                              void* d_out, int out_size, void* d_ws, size_t ws_size,
                              hipStream_t stream) {
    const float* x     = (const float*)d_in[0];
    const int*   eidx  = (const int*)d_in[1];   // [2,E] int32
    const float* eattr = (const float*)d_in[2];
    const float* u     = (const float*)d_in[3];
    const int*   batch = (const int*)d_in[4];
    const float* W1a   = (const float*)d_in[5];
    const float* b1a   = (const float*)d_in[6];
    const float* W1b   = (const float*)d_in[7];
    const float* b1b   = (const float*)d_in[8];
    const float* W2a   = (const float*)d_in[9];
    const float* b2a   = (const float*)d_in[10];
    const float* W2b   = (const float*)d_in[11];
    const float* b2b   = (const float*)d_in[12];
    float* out = (float*)d_out;

    const int N = in_sizes[0] / 32;
    const int E = in_sizes[1] / 2;
    const int* erow = eidx;
    const int* ecol = eidx + E;

    // ws: sorted4[E] | summed[N*64] f32 | counts[N] | rowstart[N+1] | cursor[N] | bsum[256]
    int4*  sorted4  = (int4*)d_ws;
    float* summed   = (float*)(sorted4 + E);
    int*   counts   = (int*)(summed + (size_t)N * 64);
    int*   rowstart = counts + N;
    int*   cursor   = rowstart + (N + 1);
    int*   bsum     = cursor + N;

    // zero summed + counts (contiguous)
    hipMemsetAsync(summed, 0, ((size_t)N * 64 + N) * sizeof(float), stream);

    count_rows<<<1024, 256, 0, stream>>>(erow, counts, E);
    const int nb = (N + 255) / 256;
    scan_blocks<<<nb, 256, 0, stream>>>(counts, rowstart, bsum, N);
    scan_bsum<<<1, 256, 0, stream>>>(bsum, nb);
    scan_add<<<nb, 256, 0, stream>>>(rowstart, bsum, N, E);
    hipMemcpyAsync(cursor, rowstart, (size_t)N * sizeof(int),
                   hipMemcpyDeviceToDevice, stream);
    permute_edges<<<1024, 256, 0, stream>>>(erow, ecol, cursor, sorted4, E);

    edge_mlp_mfma<<<4096, 256, 0, stream>>>(x, sorted4, eattr,
                                            W1a, b1a, W1b, b1b, summed, E);
    node_mlp_mfma<<<784, 256, 0, stream>>>(x, summed, rowstart, u, batch,
                                           W2a, b2a, W2b, b2b, out, N);
}

// Round 7
// 417.400 us; speedup vs baseline: 1.0021x; 1.0021x over previous
//
#include <hip/hip_runtime.h>
#include <hip/hip_bf16.h>

// NodeModel: edge MLP ([x[col]||edge_attr] -> 64 relu -> 64 relu) -> scatter_mean
// over row -> node MLP ([x||agg||u[batch]] -> 64 relu -> 32).
// N=50000, E=1.6M, D_H=64.
//
// R6: software-pipelined edge kernel. Grid-stride loop keeps sorted4 metadata
// 2 tiles ahead and the 64B/lane input gather 1 tile ahead in registers, so
// the ~900-cyc random gathers hide under the current tile's MFMA+LDS+flush
// chain (R5 was serial: 11.7K cyc/tile wall latency, VALUBusy 30%).
// Sort-chain kernels vectorized to int4 (4 edges/thread).

typedef __attribute__((ext_vector_type(8))) short bf16x8;
typedef __attribute__((ext_vector_type(4))) float f32x4;

__device__ __forceinline__ unsigned short f2bf(float f) {
    union { float f; unsigned u; } v; v.f = f;
    return (unsigned short)((v.u + 0x7FFFu + ((v.u >> 16) & 1u)) >> 16);
}

// ---------------- counting sort ----------------

__global__ __launch_bounds__(256) void count_rows(
    const int* __restrict__ erow, int* __restrict__ counts, int E)
{
    const int gid = blockIdx.x * blockDim.x + threadIdx.x;
    const int stride = gridDim.x * blockDim.x;
    const int n4 = E >> 2;
    for (int i = gid; i < n4; i += stride) {
        const int4 r = ((const int4*)erow)[i];
        atomicAdd(&counts[r.x], 1);
        atomicAdd(&counts[r.y], 1);
        atomicAdd(&counts[r.z], 1);
        atomicAdd(&counts[r.w], 1);
    }
    for (int i = (n4 << 2) + gid; i < E; i += stride)
        atomicAdd(&counts[erow[i]], 1);
}

__global__ __launch_bounds__(256) void scan_blocks(
    const int* __restrict__ counts, int* __restrict__ excl,
    int* __restrict__ bsum, int N)
{
    __shared__ int tmp[256];
    const int t = threadIdx.x;
    const int i = blockIdx.x * 256 + t;
    const int v = (i < N) ? counts[i] : 0;
    tmp[t] = v; __syncthreads();
#pragma unroll
    for (int o = 1; o < 256; o <<= 1) {
        const int a = (t >= o) ? tmp[t - o] : 0;
        __syncthreads();
        tmp[t] += a;
        __syncthreads();
    }
    if (i < N) excl[i] = tmp[t] - v;
    if (t == 255) bsum[blockIdx.x] = tmp[t];
}

__global__ __launch_bounds__(256) void scan_bsum(int* __restrict__ bsum, int nb)
{
    __shared__ int tmp[256];
    const int t = threadIdx.x;
    const int v = (t < nb) ? bsum[t] : 0;
    tmp[t] = v; __syncthreads();
#pragma unroll
    for (int o = 1; o < 256; o <<= 1) {
        const int a = (t >= o) ? tmp[t - o] : 0;
        __syncthreads();
        tmp[t] += a;
        __syncthreads();
    }
    if (t < nb) bsum[t] = tmp[t] - v;   // exclusive
}

__global__ __launch_bounds__(256) void scan_add(
    int* __restrict__ rowstart, const int* __restrict__ bsum, int N, int E)
{
    const int i = blockIdx.x * 256 + threadIdx.x;
    if (i < N) rowstart[i] += bsum[blockIdx.x];
    if (i == 0) rowstart[N] = E;
}

// sorted4[pos] = {edge_id, col, row, 0}
__global__ __launch_bounds__(256) void permute_edges(
    const int* __restrict__ erow, const int* __restrict__ ecol,
    int* __restrict__ cursor, int4* __restrict__ sorted4, int E)
{
    const int gid = blockIdx.x * blockDim.x + threadIdx.x;
    const int stride = gridDim.x * blockDim.x;
    const int n4 = E >> 2;
    for (int i = gid; i < n4; i += stride) {
        const int4 r = ((const int4*)erow)[i];
        const int4 c = ((const int4*)ecol)[i];
        const int e0 = i << 2;
        int pos;
        pos = atomicAdd(&cursor[r.x], 1); sorted4[pos] = int4{e0,     c.x, r.x, 0};
        pos = atomicAdd(&cursor[r.y], 1); sorted4[pos] = int4{e0 + 1, c.y, r.y, 0};
        pos = atomicAdd(&cursor[r.z], 1); sorted4[pos] = int4{e0 + 2, c.z, r.z, 0};
        pos = atomicAdd(&cursor[r.w], 1); sorted4[pos] = int4{e0 + 3, c.w, r.w, 0};
    }
    for (int i = (n4 << 2) + gid; i < E; i += stride) {
        const int r = erow[i];
        const int pos = atomicAdd(&cursor[r], 1);
        sorted4[pos] = int4{i, ecol[i], r, 0};
    }
}

// ---------------- edge MLP (sorted, pipelined) + segment-reduced scatter ----------------

#define D2S 68   // D2 row stride (floats); breaks the 4-way store conflict

__global__ __launch_bounds__(256, 3) void edge_mlp_mfma(
    const float* __restrict__ x,        // [N,32]
    const int4*  __restrict__ sorted4,  // [E] {eid,col,row,0}
    const float* __restrict__ eattr,    // [E,32]
    const float* __restrict__ W1a,      // [64,64] (in,out)
    const float* __restrict__ b1a,      // [64]
    const float* __restrict__ W1b,      // [64,64]
    const float* __restrict__ b1b,      // [64]
    float* __restrict__ summed,         // [N,64]
    int E)
{
    __shared__ __align__(16) unsigned short In[64 * 64];   // 8KB
    __shared__ __align__(16) unsigned short H2[64 * 64];   // 8KB
    __shared__ __align__(16) float          D2[64 * D2S];  // 17KB

    const int tid  = threadIdx.x;
    const int lane = tid & 63;
    const int wv   = tid >> 6;
    const int g    = lane >> 4;
    const int el   = lane & 15;
    const int le   = lane >> 2;   // staging: local edge 0..15
    const int p    = lane & 3;    // staging: quarter of 64-wide input

    // persistent weight fragments: A row = lane&15, k = 8*(lane>>4)+j;
    // B col = lane&15, same k (identical mappings)
    bf16x8 wa[4][2], wb[4][2];
    f32x4  bias1[4];
    float  bias2s[4];
#pragma unroll
    for (int mt = 0; mt < 4; ++mt) {
        const int o = mt * 16 + el;
#pragma unroll
        for (int ks = 0; ks < 2; ++ks) {
            bf16x8 ta, tb;
#pragma unroll
            for (int j = 0; j < 8; ++j) {
                const int k = ks * 32 + 8 * g + j;
                ta[j] = (short)f2bf(W1a[k * 64 + o]);
                tb[j] = (short)f2bf(W1b[k * 64 + o]);
            }
            wa[mt][ks] = ta;
            wb[mt][ks] = tb;
        }
#pragma unroll
        for (int r = 0; r < 4; ++r) bias1[mt][r] = b1a[mt * 16 + 4 * g + r];
        bias2s[mt] = b1b[o];
    }

    unsigned short* const inrow = In + (wv * 16) * 64;
    unsigned short* const h2row = H2 + (wv * 16) * 64;
    float*          const d2row = D2 + (wv * 16) * D2S;

    const int ntile = (E + 15) >> 4;
    const int wid   = blockIdx.x * 4 + wv;
    const int nw    = gridDim.x * 4;

    // tile-meta load (sorted4 fragments needed by staging + flush)
    auto load_meta = [&](int t, int4& s4o, int& mro) {
        if (t < ntile) {
            const int ebase = t << 4;
            const int pos  = ebase + le;
            const int pos2 = ebase + el;
            s4o = (pos  < E) ? sorted4[pos] : int4{0, 0, 0, 0};
            mro = (pos2 < E) ? sorted4[pos2].z : -1;
        } else {
            s4o = int4{0, 0, 0, 0};
            mro = -1;
        }
    };
    // input gather for tile t using its meta (64B/lane)
    auto gather = [&](int t, const int4& s4, float4 vo[4]) {
        const bool valid = (t < ntile) && (((t << 4) + le) < E);
        const float* src = (p < 2) ? x + (size_t)s4.y * 32 + p * 16
                                   : eattr + (size_t)s4.x * 32 + (p - 2) * 16;
        if (valid) {
#pragma unroll
            for (int q = 0; q < 4; ++q) vo[q] = ((const float4*)src)[q];
        } else {
#pragma unroll
            for (int q = 0; q < 4; ++q) vo[q] = float4{0.f, 0.f, 0.f, 0.f};
        }
    };

    // ---- pipeline prologue: meta(t), gather(t), meta(t+nw) ----
    float4 vc[4]; int mrc;
    int4 s4p; int mrp;
    {
        int4 s4c; int mr0;
        load_meta(wid, s4c, mr0);
        gather(wid, s4c, vc);
        mrc = mr0;
        load_meta(wid + nw, s4p, mrp);
    }

    for (int t = wid; t < ntile; t += nw) {
        const int ebase = t << 4;

        // ---- prefetch issues: meta for t+2nw, gather for t+nw ----
        int4 s4p2; int mrp2;
        load_meta(t + 2 * nw, s4p2, mrp2);
        float4 vn[4];
        gather(t + nw, s4p, vn);

        // ---- stage current tile: pack vc -> bf16 -> swizzled LDS ----
        {
            bf16x8 c0, c1;
#pragma unroll
            for (int q = 0; q < 2; ++q) {
                c0[4*q+0] = (short)f2bf(vc[q].x);   c0[4*q+1] = (short)f2bf(vc[q].y);
                c0[4*q+2] = (short)f2bf(vc[q].z);   c0[4*q+3] = (short)f2bf(vc[q].w);
                c1[4*q+0] = (short)f2bf(vc[q+2].x); c1[4*q+1] = (short)f2bf(vc[q+2].y);
                c1[4*q+2] = (short)f2bf(vc[q+2].z); c1[4*q+3] = (short)f2bf(vc[q+2].w);
            }
            const int sw = le & 7;
            unsigned short* row = inrow + le * 64;
            *(bf16x8*)(row + (((2 * p)     ^ sw) * 8)) = c0;
            *(bf16x8*)(row + (((2 * p + 1) ^ sw) * 8)) = c1;
        }
        // wave-private LDS rows: compiler lgkmcnt orders write->read, no barrier

        const int sw = el & 7;

        // ---- layer 1: D1 = W1a^T (A) x In^T (B) -> neuron-major ----
        const unsigned short* brow = inrow + el * 64;
        const bf16x8 bf0 = *(const bf16x8*)(brow + (((0 + g) ^ sw) * 8));
        const bf16x8 bf1 = *(const bf16x8*)(brow + (((4 + g) ^ sw) * 8));
        f32x4 a0 = bias1[0], a1 = bias1[1], a2 = bias1[2], a3 = bias1[3];
        a0 = __builtin_amdgcn_mfma_f32_16x16x32_bf16(wa[0][0], bf0, a0, 0, 0, 0);
        a1 = __builtin_amdgcn_mfma_f32_16x16x32_bf16(wa[1][0], bf0, a1, 0, 0, 0);
        a2 = __builtin_amdgcn_mfma_f32_16x16x32_bf16(wa[2][0], bf0, a2, 0, 0, 0);
        a3 = __builtin_amdgcn_mfma_f32_16x16x32_bf16(wa[3][0], bf0, a3, 0, 0, 0);
        a0 = __builtin_amdgcn_mfma_f32_16x16x32_bf16(wa[0][1], bf1, a0, 0, 0, 0);
        a1 = __builtin_amdgcn_mfma_f32_16x16x32_bf16(wa[1][1], bf1, a1, 0, 0, 0);
        a2 = __builtin_amdgcn_mfma_f32_16x16x32_bf16(wa[2][1], bf1, a2, 0, 0, 0);
        a3 = __builtin_amdgcn_mfma_f32_16x16x32_bf16(wa[3][1], bf1, a3, 0, 0, 0);

        // ---- relu -> bf16 -> H2 (wave-private, swizzled) ----
        unsigned short* hrow = h2row + el * 64;
        {
            f32x4 accs[4] = {a0, a1, a2, a3};
#pragma unroll
            for (int mt = 0; mt < 4; ++mt) {
                unsigned short pk[4];
#pragma unroll
                for (int r = 0; r < 4; ++r) pk[r] = f2bf(fmaxf(accs[mt][r], 0.f));
                const int hid   = mt * 16 + 4 * g;
                const int chunk = hid >> 3;
                const int off   = hid & 7;
                *(uint2*)(hrow + ((chunk ^ sw) * 8 + off)) = *(uint2*)pk;
            }
        }

        // ---- layer 2, operand-swapped: D2 = H1 (A) x W1b (B) -> EDGE-major ----
        const bf16x8 hb0 = *(const bf16x8*)(hrow + (((0 + g) ^ sw) * 8));
        const bf16x8 hb1 = *(const bf16x8*)(hrow + (((4 + g) ^ sw) * 8));
        f32x4 d0 = {bias2s[0], bias2s[0], bias2s[0], bias2s[0]};
        f32x4 d1 = {bias2s[1], bias2s[1], bias2s[1], bias2s[1]};
        f32x4 d2 = {bias2s[2], bias2s[2], bias2s[2], bias2s[2]};
        f32x4 d3 = {bias2s[3], bias2s[3], bias2s[3], bias2s[3]};
        d0 = __builtin_amdgcn_mfma_f32_16x16x32_bf16(hb0, wb[0][0], d0, 0, 0, 0);
        d1 = __builtin_amdgcn_mfma_f32_16x16x32_bf16(hb0, wb[1][0], d1, 0, 0, 0);
        d2 = __builtin_amdgcn_mfma_f32_16x16x32_bf16(hb0, wb[2][0], d2, 0, 0, 0);
        d3 = __builtin_amdgcn_mfma_f32_16x16x32_bf16(hb0, wb[3][0], d3, 0, 0, 0);
        d0 = __builtin_amdgcn_mfma_f32_16x16x32_bf16(hb1, wb[0][1], d0, 0, 0, 0);
        d1 = __builtin_amdgcn_mfma_f32_16x16x32_bf16(hb1, wb[1][1], d1, 0, 0, 0);
        d2 = __builtin_amdgcn_mfma_f32_16x16x32_bf16(hb1, wb[2][1], d2, 0, 0, 0);
        d3 = __builtin_amdgcn_mfma_f32_16x16x32_bf16(hb1, wb[3][1], d3, 0, 0, 0);

        // ---- relu -> LDS [16 edges][64 neurons] f32 (stride D2S) ----
        {
            f32x4 dd[4] = {d0, d1, d2, d3};
#pragma unroll
            for (int nt = 0; nt < 4; ++nt)
#pragma unroll
                for (int r = 0; r < 4; ++r) {
                    const int eg = ebase + 4 * g + r;
                    d2row[(4 * g + r) * D2S + nt * 16 + el] =
                        (eg < E) ? fmaxf(dd[nt][r], 0.f) : 0.f;
                }
        }

        // ---- segment flush: rows are sorted runs; lane = neuron ----
        float acc = 0.f;
        int prev = __shfl(mrc, 0);
#pragma unroll
        for (int j = 0; j < 16; ++j) {
            const float v = d2row[j * D2S + lane];
            const int rj = __shfl(mrc, j);
            if (rj != prev) {                        // wave-uniform branch
                if (prev >= 0)
                    unsafeAtomicAdd(&summed[(size_t)prev * 64 + lane], acc);
                acc = 0.f;
                prev = rj;
            }
            acc += v;
        }
        if (prev >= 0)
            unsafeAtomicAdd(&summed[(size_t)prev * 64 + lane], acc);

        // ---- rotate pipeline registers ----
#pragma unroll
        for (int q = 0; q < 4; ++q) vc[q] = vn[q];
        mrc = mrp;
        s4p = s4p2;
        mrp = mrp2;
    }
}

// ---------------- node MLP via MFMA ----------------

__global__ __launch_bounds__(256, 2) void node_mlp_mfma(
    const float* __restrict__ x,        // [N,32]
    const float* __restrict__ summed,   // [N,64]
    const int*   __restrict__ rowstart, // [N+1]
    const float* __restrict__ u,        // [G,16]
    const int*   __restrict__ batch,    // [N]
    const float* __restrict__ W2a,      // [112,64]
    const float* __restrict__ b2a,      // [64]
    const float* __restrict__ W2b,      // [64,32]
    const float* __restrict__ b2b,      // [32]
    float* __restrict__ out,            // [N,32]
    int N)
{
    __shared__ __align__(16) unsigned short In[64 * 128];  // 16KB
    __shared__ __align__(16) unsigned short H[64 * 64];    // 8KB

    const int tid  = threadIdx.x;
    const int lane = tid & 63;
    const int wv   = tid >> 6;
    const int g    = lane >> 4;
    const int el   = lane & 15;

    bf16x8 wa[4][4];
    f32x4  bias1[4];
#pragma unroll
    for (int mt = 0; mt < 4; ++mt) {
        const int o = mt * 16 + el;
#pragma unroll
        for (int ks = 0; ks < 4; ++ks) {
            bf16x8 ta;
#pragma unroll
            for (int j = 0; j < 8; ++j) {
                const int k = ks * 32 + 8 * g + j;
                ta[j] = (k < 112) ? (short)f2bf(W2a[k * 64 + o]) : (short)0;
            }
            wa[mt][ks] = ta;
        }
#pragma unroll
        for (int r = 0; r < 4; ++r) bias1[mt][r] = b2a[mt * 16 + 4 * g + r];
    }
    bf16x8 wb[2][2];
    float  bias2s[2];
#pragma unroll
    for (int nt = 0; nt < 2; ++nt) {
        const int o = nt * 16 + el;
#pragma unroll
        for (int ks = 0; ks < 2; ++ks) {
            bf16x8 tb;
#pragma unroll
            for (int j = 0; j < 8; ++j) {
                const int k = ks * 32 + 8 * g + j;
                tb[j] = (short)f2bf(W2b[k * 32 + o]);
            }
            wb[nt][ks] = tb;
        }
        bias2s[nt] = b2b[o];
    }

    unsigned short* const inrow = In + (wv * 16) * 128;
    unsigned short* const hrow0 = H + (wv * 16) * 64;

    const int ntile = (N + 15) >> 4;
    const int wid   = blockIdx.x * 4 + wv;
    const int nw    = gridDim.x * 4;

    for (int t = wid; t < ntile; t += nw) {
        const int nbase = t << 4;

        // ---- stage 16 nodes: 4 lanes/node, 32-float segment each ----
        // row layout (128 bf16): [x(32) | agg(32) | agg(32) | u(16)+0(16)]
        {
            const int le = lane >> 2;
            const int p  = lane & 3;
            const int n  = nbase + le;
            float4 v[8];
            if (n < N) {
                if (p == 0) {
                    const float4* xp = (const float4*)(x + (size_t)n * 32);
#pragma unroll
                    for (int q = 0; q < 8; ++q) v[q] = xp[q];
                } else if (p < 3) {
                    const int cnt = rowstart[n + 1] - rowstart[n];
                    const float inv = 1.0f / fmaxf((float)cnt, 1.0f);
                    const float4* sp = (const float4*)(summed + (size_t)n * 64 + (p - 1) * 32);
#pragma unroll
                    for (int q = 0; q < 8; ++q) {
                        v[q] = sp[q];
                        v[q].x *= inv; v[q].y *= inv; v[q].z *= inv; v[q].w *= inv;
                    }
                } else {
                    const int gb = batch[n];
                    const float4* up = (const float4*)(u + (size_t)gb * 16);
#pragma unroll
                    for (int q = 0; q < 4; ++q) v[q] = up[q];
#pragma unroll
                    for (int q = 4; q < 8; ++q) v[q] = float4{0.f, 0.f, 0.f, 0.f};
                }
            } else {
#pragma unroll
                for (int q = 0; q < 8; ++q) v[q] = float4{0.f, 0.f, 0.f, 0.f};
            }
            const int sw = le & 7;
            unsigned short* row = inrow + le * 128;
#pragma unroll
            for (int q = 0; q < 4; ++q) {
                bf16x8 c;
                const float4 va = v[2 * q], vb = v[2 * q + 1];
                c[0] = (short)f2bf(va.x); c[1] = (short)f2bf(va.y);
                c[2] = (short)f2bf(va.z); c[3] = (short)f2bf(va.w);
                c[4] = (short)f2bf(vb.x); c[5] = (short)f2bf(vb.y);
                c[6] = (short)f2bf(vb.z); c[7] = (short)f2bf(vb.w);
                const int cc = 4 * p + q;
                const int ci = (cc & 8) | ((cc & 7) ^ sw);
                *(bf16x8*)(row + ci * 8) = c;
            }
        }

        // ---- layer 1: 16 MFMAs over K=128 ----
        const unsigned short* brow = inrow + el * 128;
        const int sw7 = el & 7;
        f32x4 a0 = bias1[0], a1 = bias1[1], a2 = bias1[2], a3 = bias1[3];
#pragma unroll
        for (int ks = 0; ks < 4; ++ks) {
            const int cc = ks * 4 + g;
            const int ci = (cc & 8) | ((cc & 7) ^ sw7);
            const bf16x8 bf = *(const bf16x8*)(brow + ci * 8);
            a0 = __builtin_amdgcn_mfma_f32_16x16x32_bf16(wa[0][ks], bf, a0, 0, 0, 0);
            a1 = __builtin_amdgcn_mfma_f32_16x16x32_bf16(wa[1][ks], bf, a1, 0, 0, 0);
            a2 = __builtin_amdgcn_mfma_f32_16x16x32_bf16(wa[2][ks], bf, a2, 0, 0, 0);
            a3 = __builtin_amdgcn_mfma_f32_16x16x32_bf16(wa[3][ks], bf, a3, 0, 0, 0);
        }

        // ---- relu -> bf16 -> H (swizzled by el&7) ----
        unsigned short* hrow = hrow0 + el * 64;
        {
            f32x4 accs[4] = {a0, a1, a2, a3};
#pragma unroll
            for (int mt = 0; mt < 4; ++mt) {
                unsigned short pk[4];
#pragma unroll
                for (int r = 0; r < 4; ++r) pk[r] = f2bf(fmaxf(accs[mt][r], 0.f));
                const int hid   = mt * 16 + 4 * g;
                const int chunk = hid >> 3;
                const int off   = hid & 7;
                *(uint2*)(hrow + ((chunk ^ sw7) * 8 + off)) = *(uint2*)pk;
            }
        }

        // ---- layer 2 operand-swapped: D = H (A) x W2b (B) -> node-major ----
        const bf16x8 hb0 = *(const bf16x8*)(hrow + (((0 + g) ^ sw7) * 8));
        const bf16x8 hb1 = *(const bf16x8*)(hrow + (((4 + g) ^ sw7) * 8));
        f32x4 dn0 = {bias2s[0], bias2s[0], bias2s[0], bias2s[0]};
        f32x4 dn1 = {bias2s[1], bias2s[1], bias2s[1], bias2s[1]};
        dn0 = __builtin_amdgcn_mfma_f32_16x16x32_bf16(hb0, wb[0][0], dn0, 0, 0, 0);
        dn1 = __builtin_amdgcn_mfma_f32_16x16x32_bf16(hb0, wb[1][0], dn1, 0, 0, 0);
        dn0 = __builtin_amdgcn_mfma_f32_16x16x32_bf16(hb1, wb[0][1], dn0, 0, 0, 0);
        dn1 = __builtin_amdgcn_mfma_f32_16x16x32_bf16(hb1, wb[1][1], dn1, 0, 0, 0);

        // ---- store: lane holds node 4g+r, out nt*16+el ----
        if (nbase + 16 <= N) {
#pragma unroll
            for (int r = 0; r < 4; ++r) {
                float* dst = out + (size_t)(nbase + 4 * g + r) * 32 + el;
                dst[0]  = dn0[r];
                dst[16] = dn1[r];
            }
        } else {
#pragma unroll
            for (int r = 0; r < 4; ++r) {
                const int n = nbase + 4 * g + r;
                if (n < N) {
                    float* dst = out + (size_t)n * 32 + el;
                    dst[0]  = dn0[r];
                    dst[16] = dn1[r];
                }
            }
        }
    }
}

extern "C" void kernel_launch(void* const* d_in, const int* in_sizes, int n_in,
                              void* d_out, int out_size, void* d_ws, size_t ws_size,
                              hipStream_t stream) {
    const float* x     = (const float*)d_in[0];
    const int*   eidx  = (const int*)d_in[1];   // [2,E] int32
    const float* eattr = (const float*)d_in[2];
    const float* u     = (const float*)d_in[3];
    const int*   batch = (const int*)d_in[4];
    const float* W1a   = (const float*)d_in[5];
    const float* b1a   = (const float*)d_in[6];
    const float* W1b   = (const float*)d_in[7];
    const float* b1b   = (const float*)d_in[8];
    const float* W2a   = (const float*)d_in[9];
    const float* b2a   = (const float*)d_in[10];
    const float* W2b   = (const float*)d_in[11];
    const float* b2b   = (const float*)d_in[12];
    float* out = (float*)d_out;

    const int N = in_sizes[0] / 32;
    const int E = in_sizes[1] / 2;
    const int* erow = eidx;
    const int* ecol = eidx + E;

    // ws: sorted4[E] | summed[N*64] f32 | counts[N] | rowstart[N+1] | cursor[N] | bsum[256]
    int4*  sorted4  = (int4*)d_ws;
    float* summed   = (float*)(sorted4 + E);
    int*   counts   = (int*)(summed + (size_t)N * 64);
    int*   rowstart = counts + N;
    int*   cursor   = rowstart + (N + 1);
    int*   bsum     = cursor + N;

    // zero summed + counts (contiguous)
    hipMemsetAsync(summed, 0, ((size_t)N * 64 + N) * sizeof(float), stream);

    count_rows<<<1024, 256, 0, stream>>>(erow, counts, E);
    const int nb = (N + 255) / 256;
    scan_blocks<<<nb, 256, 0, stream>>>(counts, rowstart, bsum, N);
    scan_bsum<<<1, 256, 0, stream>>>(bsum, nb);
    scan_add<<<nb, 256, 0, stream>>>(rowstart, bsum, N, E);
    hipMemcpyAsync(cursor, rowstart, (size_t)N * sizeof(int),
                   hipMemcpyDeviceToDevice, stream);
    permute_edges<<<1024, 256, 0, stream>>>(erow, ecol, cursor, sorted4, E);

    edge_mlp_mfma<<<4096, 256, 0, stream>>>(x, sorted4, eattr,
                                            W1a, b1a, W1b, b1b, summed, E);
    node_mlp_mfma<<<784, 256, 0, stream>>>(x, summed, rowstart, u, batch,
                                           W2a, b2a, W2b, b2b, out, N);
}